// Round 1
// baseline (304.204 us; speedup 1.0000x reference)
//
#include <hip/hip_runtime.h>
#include <hip/hip_bf16.h>
#include <math.h>

// SelfRetentionV1: B=2,H=16,L=2048,DK=128,DV=128
// out[b,l,h,d] = RMSNorm_d( (QK^T * gamma^(i-j) / max(1,|rowsum|)) @ V )
#define B_ 2
#define H_ 16
#define L_ 2048
#define DK_ 128
#define DV_ 128
#define QBLK 64
#define KVBLK 64
#define NIT (L_/QBLK)   // 32

typedef __bf16 bf16x8 __attribute__((ext_vector_type(8)));
typedef float  f32x4  __attribute__((ext_vector_type(4)));

static __device__ __forceinline__ unsigned short f2bf(float f) {
    union { float f; unsigned int u; } x; x.f = f;
    unsigned int r = x.u + 0x7fffu + ((x.u >> 16) & 1u);  // RNE
    return (unsigned short)(r >> 16);
}

// ---- pre-kernel 1: fp32 -> bf16 flat convert (K) ----
__global__ void cvt_bf16_kernel(const float* __restrict__ in,
                                unsigned short* __restrict__ out, int n4) {
    int i = blockIdx.x * blockDim.x + threadIdx.x;
    int stride = gridDim.x * blockDim.x;
    for (; i < n4; i += stride) {
        float4 f = ((const float4*)in)[i];
        uint2 o;
        o.x = (unsigned)f2bf(f.x) | ((unsigned)f2bf(f.y) << 16);
        o.y = (unsigned)f2bf(f.z) | ((unsigned)f2bf(f.w) << 16);
        ((uint2*)out)[i] = o;
    }
}

// ---- pre-kernel 2: V[bh][l][dv] -> VT[bh][dv][l], bf16 ----
__global__ void transpose_v_kernel(const float* __restrict__ v,
                                   unsigned short* __restrict__ vt) {
    __shared__ unsigned short lds[64][130];   // +2 pad: col reads conflict-free
    int blk = blockIdx.x;
    int ltile = blk & (L_/64 - 1);
    int bh = blk / (L_/64);
    const float* vp = v + ((size_t)bh * L_ + (size_t)ltile * 64) * DV_;
    unsigned short* vo = vt + (size_t)bh * DV_ * L_ + ltile * 64;
    int t = threadIdx.x;
    int r0 = t >> 5, c0 = (t & 31) * 4;
    #pragma unroll
    for (int it = 0; it < 8; ++it) {
        int row = r0 + 8 * it;
        float4 f = *(const float4*)(vp + row * DV_ + c0);
        lds[row][c0 + 0] = f2bf(f.x);
        lds[row][c0 + 1] = f2bf(f.y);
        lds[row][c0 + 2] = f2bf(f.z);
        lds[row][c0 + 3] = f2bf(f.w);
    }
    __syncthreads();
    int dvb = t >> 3, seg = t & 7;
    #pragma unroll
    for (int ot = 0; ot < 4; ++ot) {
        int dv = dvb + 32 * ot;
        unsigned short a0 = lds[seg*8+0][dv], a1 = lds[seg*8+1][dv];
        unsigned short a2 = lds[seg*8+2][dv], a3 = lds[seg*8+3][dv];
        unsigned short a4 = lds[seg*8+4][dv], a5 = lds[seg*8+5][dv];
        unsigned short a6 = lds[seg*8+6][dv], a7 = lds[seg*8+7][dv];
        uint4 st;
        st.x = (unsigned)a0 | ((unsigned)a1 << 16);
        st.y = (unsigned)a2 | ((unsigned)a3 << 16);
        st.z = (unsigned)a4 | ((unsigned)a5 << 16);
        st.w = (unsigned)a6 | ((unsigned)a7 << 16);
        *(uint4*)(vo + (size_t)dv * L_ + seg * 8) = st;
    }
}

// ---- main kernel: 4 waves, each owns 16 Q-rows; KV tiles of 64 ----
__launch_bounds__(256, 4)
__global__ void retention_kernel(const float* __restrict__ q,
                                 const unsigned short* __restrict__ kb,
                                 const unsigned short* __restrict__ vt_,
                                 float* __restrict__ out) {
    // P round-trip buffer, wave-private. Row stride 72*2=144B (16B-mult, pad
    // breaks the 128B-stride bank alias; b128 reads spread 8 lanes/4-bank grp)
    __shared__ __align__(16) unsigned short p_lds[4][16][72];

    // reflected itile mapping: balances causal work across CUs if round-robin
    int kk = blockIdx.x >> 8;           // 0..3
    int m  = blockIdx.x & 255;
    int slot = m >> 5;                  // 0..7
    int bh = m & 31;
    int itile = 8 * kk + ((kk & 1) ? (7 - slot) : slot);
    int b = bh >> 4, h = bh & 15;

    int lane = threadIdx.x & 63;
    int w = threadIdx.x >> 6;
    int g = lane >> 4;                  // 0..3
    int c = lane & 15;                  // 0..15

    int i_wave = itile * QBLK + w * 16;

    float ex = exp2f((float)(-5 - h));
    float gamma = 1.0f - ex;
    float log2g = log1pf(-ex) * 1.44269504088896f;   // accurate near gamma~1

    // column decay factors: gamma^-(16*nt + c)   (max gamma^-63 ~ 7.4, safe)
    float bcol[4];
    bcol[0] = exp2f(log2g * (float)(-c));
    float g16i = exp2f(log2g * (-16.0f));
    bcol[1] = bcol[0] * g16i; bcol[2] = bcol[1] * g16i; bcol[3] = bcol[2] * g16i;

    // hoist Q fragments (A operand: m = lane&15, k contiguous per 16-lane grp)
    bf16x8 qf[4];
    {
        const float* qp = q + ((size_t)bh * L_ + (i_wave + c)) * DK_ + g * 8;
        #pragma unroll
        for (int ks = 0; ks < 4; ++ks) {
            float4 f0 = *(const float4*)(qp + ks * 32);
            float4 f1 = *(const float4*)(qp + ks * 32 + 4);
            union { bf16x8 v; unsigned short u[8]; } A;
            A.u[0]=f2bf(f0.x); A.u[1]=f2bf(f0.y); A.u[2]=f2bf(f0.z); A.u[3]=f2bf(f0.w);
            A.u[4]=f2bf(f1.x); A.u[5]=f2bf(f1.y); A.u[6]=f2bf(f1.z); A.u[7]=f2bf(f1.w);
            qf[ks] = A.v;
        }
    }

    const unsigned short* kbp = kb  + (size_t)bh * L_ * DK_;
    const unsigned short* vtp = vt_ + (size_t)bh * DV_ * L_;

    f32x4 o[8];
    f32x4 zero = {0.f, 0.f, 0.f, 0.f};
    #pragma unroll
    for (int nt = 0; nt < 8; ++nt) o[nt] = zero;
    float rowsum[4] = {0.f, 0.f, 0.f, 0.f};

    for (int jt = 0; jt <= itile; ++jt) {
        int j_base = jt * KVBLK;

        // ---- S = Q K^T (16x64), B-frags straight from bf16 K (gemm_bt style)
        f32x4 s[4];
        #pragma unroll
        for (int nt = 0; nt < 4; ++nt) s[nt] = zero;
        #pragma unroll
        for (int ks = 0; ks < 4; ++ks) {
            #pragma unroll
            for (int nt = 0; nt < 4; ++nt) {
                const unsigned short* kp =
                    kbp + (size_t)(j_base + nt * 16 + c) * DK_ + ks * 32 + g * 8;
                bf16x8 bfrag = *(const bf16x8*)kp;
                s[nt] = __builtin_amdgcn_mfma_f32_16x16x32_bf16(qf[ks], bfrag, s[nt], 0, 0, 0);
            }
        }

        // ---- decay: w(i,j) = gamma^(i - j_base) * gamma^-(j - j_base)
        int di0 = i_wave + g * 4 - j_base;           // >= 0 always
        float arow[4];
        arow[0] = exp2f(log2g * (float)di0);
        arow[1] = arow[0] * gamma; arow[2] = arow[1] * gamma; arow[3] = arow[2] * gamma;

        if (jt == itile) {   // diagonal tile: per-element causal mask
            #pragma unroll
            for (int nt = 0; nt < 4; ++nt) {
                int j = j_base + nt * 16 + c;
                #pragma unroll
                for (int r = 0; r < 4; ++r) {
                    int i = i_wave + g * 4 + r;
                    float wgt = (j <= i) ? arow[r] * bcol[nt] : 0.0f;
                    float val = s[nt][r] * wgt;
                    rowsum[r] += val;
                    p_lds[w][g * 4 + r][nt * 16 + c] = f2bf(val);
                }
            }
        } else {             // strictly-lower tile: no mask needed
            #pragma unroll
            for (int nt = 0; nt < 4; ++nt) {
                #pragma unroll
                for (int r = 0; r < 4; ++r) {
                    float val = s[nt][r] * (arow[r] * bcol[nt]);
                    rowsum[r] += val;
                    p_lds[w][g * 4 + r][nt * 16 + c] = f2bf(val);
                }
            }
        }
        __syncthreads();     // cross-lane P visibility (uniform trip count)

        // ---- O += P V ; B-frags straight from bf16 V^T
        #pragma unroll
        for (int ks = 0; ks < 2; ++ks) {
            bf16x8 pa = *(const bf16x8*)&p_lds[w][c][ks * 32 + g * 8];
            #pragma unroll
            for (int nt = 0; nt < 8; ++nt) {
                const unsigned short* vp =
                    vtp + (size_t)(nt * 16 + c) * L_ + j_base + ks * 32 + g * 8;
                bf16x8 vb = *(const bf16x8*)vp;
                o[nt] = __builtin_amdgcn_mfma_f32_16x16x32_bf16(pa, vb, o[nt], 0, 0, 0);
            }
        }
        __syncthreads();     // protect p_lds before next tile's overwrite
    }

    // ---- epilogue: denom + RMSNorm (reductions within 16-lane groups) ----
    #pragma unroll
    for (int r = 0; r < 4; ++r) {
        float vsum = rowsum[r];
        vsum += __shfl_xor(vsum, 1);
        vsum += __shfl_xor(vsum, 2);
        vsum += __shfl_xor(vsum, 4);
        vsum += __shfl_xor(vsum, 8);
        rowsum[r] = 1.0f / fmaxf(1.0f, fabsf(vsum));
    }
    #pragma unroll
    for (int nt = 0; nt < 8; ++nt) {
        #pragma unroll
        for (int r = 0; r < 4; ++r) o[nt][r] *= rowsum[r];
    }
    float scale[4];
    #pragma unroll
    for (int r = 0; r < 4; ++r) {
        float ss = 0.f;
        #pragma unroll
        for (int nt = 0; nt < 8; ++nt) ss += o[nt][r] * o[nt][r];
        ss += __shfl_xor(ss, 1);
        ss += __shfl_xor(ss, 2);
        ss += __shfl_xor(ss, 4);
        ss += __shfl_xor(ss, 8);
        scale[r] = rsqrtf(ss * (1.0f / 128.0f) + 1e-6f);
    }
    #pragma unroll
    for (int r = 0; r < 4; ++r) {
        int i = i_wave + g * 4 + r;
        float* op = out + (((size_t)b * L_ + i) * H_ + h) * DV_ + c;
        #pragma unroll
        for (int nt = 0; nt < 8; ++nt) op[nt * 16] = o[nt][r] * scale[r];
    }
}

// ---- fp32 fixup for row i=0 (single-term row: eps-magnified bf16 error) ----
__global__ void fix_row0_kernel(const float* __restrict__ q,
                                const float* __restrict__ k,
                                const float* __restrict__ v,
                                float* __restrict__ out) {
    int bh = blockIdx.x;            // 0..31
    int lane = threadIdx.x;         // 0..63
    const float* qp = q + (size_t)bh * L_ * DK_;
    const float* kp = k + (size_t)bh * L_ * DK_;
    const float* vp = v + (size_t)bh * L_ * DV_;
    float part = qp[lane] * kp[lane] + qp[lane + 64] * kp[lane + 64];
    #pragma unroll
    for (int mm = 1; mm < 64; mm <<= 1) part += __shfl_xor(part, mm);
    float r00 = part;
    float cf = r00 / fmaxf(1.0f, fabsf(r00));
    float o0 = cf * vp[lane], o1 = cf * vp[lane + 64];
    float ss = o0 * o0 + o1 * o1;
    #pragma unroll
    for (int mm = 1; mm < 64; mm <<= 1) ss += __shfl_xor(ss, mm);
    float sc = rsqrtf(ss * (1.0f / 128.0f) + 1e-6f);
    int b = bh >> 4, h = bh & 15;
    float* op = out + ((size_t)b * L_ * H_ + h) * DV_;   // i = 0
    op[lane] = o0 * sc;
    op[lane + 64] = o1 * sc;
}

extern "C" void kernel_launch(void* const* d_in, const int* in_sizes, int n_in,
                              void* d_out, int out_size, void* d_ws, size_t ws_size,
                              hipStream_t stream) {
    const float* q = (const float*)d_in[0];
    const float* k = (const float*)d_in[1];
    const float* v = (const float*)d_in[2];
    // d_in[3] decay_mask (256MB) and d_in[4] intra_decay are recomputed on the fly
    float* out = (float*)d_out;

    unsigned short* kb = (unsigned short*)d_ws;                 // 16 MB
    unsigned short* vt = kb + (size_t)B_ * H_ * L_ * DK_;       // 16 MB

    int n4 = B_ * H_ * L_ * DK_ / 4;
    cvt_bf16_kernel<<<2048, 256, 0, stream>>>(k, kb, n4);
    transpose_v_kernel<<<B_ * H_ * (L_ / 64), 256, 0, stream>>>(v, vt);
    retention_kernel<<<B_ * H_ * NIT, 256, 0, stream>>>(q, kb, vt, out);
    fix_row0_kernel<<<B_ * H_, 64, 0, stream>>>(q, k, v, out);
}

// Round 2
// 290.751 us; speedup vs baseline: 1.0463x; 1.0463x over previous
//
#include <hip/hip_runtime.h>
#include <hip/hip_bf16.h>
#include <math.h>

// SelfRetentionV1: B=2,H=16,L=2048,DK=128,DV=128
// out[b,l,h,d] = RMSNorm_d( (QK^T * gamma^(i-j) / max(1,|rowsum|)) @ V )
#define B_ 2
#define H_ 16
#define L_ 2048
#define DK_ 128
#define DV_ 128
#define QBLK 64
#define KVBLK 64
#define NIT (L_/QBLK)   // 32

typedef __bf16 bf16x8 __attribute__((ext_vector_type(8)));
typedef float  f32x4  __attribute__((ext_vector_type(4)));

static __device__ __forceinline__ unsigned short f2bf(float f) {
    union { float f; unsigned int u; } x; x.f = f;
    unsigned int r = x.u + 0x7fffu + ((x.u >> 16) & 1u);  // RNE
    return (unsigned short)(r >> 16);
}

// ---- pre-kernel 1: fp32 -> bf16 flat convert (K) ----
__global__ void cvt_bf16_kernel(const float* __restrict__ in,
                                unsigned short* __restrict__ out, int n4) {
    int i = blockIdx.x * blockDim.x + threadIdx.x;
    int stride = gridDim.x * blockDim.x;
    for (; i < n4; i += stride) {
        float4 f = ((const float4*)in)[i];
        uint2 o;
        o.x = (unsigned)f2bf(f.x) | ((unsigned)f2bf(f.y) << 16);
        o.y = (unsigned)f2bf(f.z) | ((unsigned)f2bf(f.w) << 16);
        ((uint2*)out)[i] = o;
    }
}

// ---- pre-kernel 2: V[bh][l][dv] -> VT[bh][dv][l], bf16 ----
__global__ void transpose_v_kernel(const float* __restrict__ v,
                                   unsigned short* __restrict__ vt) {
    __shared__ unsigned short lds[64][130];   // +2 pad: col reads conflict-free
    int blk = blockIdx.x;
    int ltile = blk & (L_/64 - 1);
    int bh = blk / (L_/64);
    const float* vp = v + ((size_t)bh * L_ + (size_t)ltile * 64) * DV_;
    unsigned short* vo = vt + (size_t)bh * DV_ * L_ + ltile * 64;
    int t = threadIdx.x;
    int r0 = t >> 5, c0 = (t & 31) * 4;
    #pragma unroll
    for (int it = 0; it < 8; ++it) {
        int row = r0 + 8 * it;
        float4 f = *(const float4*)(vp + row * DV_ + c0);
        lds[row][c0 + 0] = f2bf(f.x);
        lds[row][c0 + 1] = f2bf(f.y);
        lds[row][c0 + 2] = f2bf(f.z);
        lds[row][c0 + 3] = f2bf(f.w);
    }
    __syncthreads();
    int dvb = t >> 3, seg = t & 7;
    #pragma unroll
    for (int ot = 0; ot < 4; ++ot) {
        int dv = dvb + 32 * ot;
        unsigned short a0 = lds[seg*8+0][dv], a1 = lds[seg*8+1][dv];
        unsigned short a2 = lds[seg*8+2][dv], a3 = lds[seg*8+3][dv];
        unsigned short a4 = lds[seg*8+4][dv], a5 = lds[seg*8+5][dv];
        unsigned short a6 = lds[seg*8+6][dv], a7 = lds[seg*8+7][dv];
        uint4 st;
        st.x = (unsigned)a0 | ((unsigned)a1 << 16);
        st.y = (unsigned)a2 | ((unsigned)a3 << 16);
        st.z = (unsigned)a4 | ((unsigned)a5 << 16);
        st.w = (unsigned)a6 | ((unsigned)a7 << 16);
        *(uint4*)(vo + (size_t)dv * L_ + seg * 8) = st;
    }
}

// ---- main kernel: 4 waves, each owns 16 Q-rows; KV tiles of 64 ----
__launch_bounds__(256, 4)
__global__ void retention_kernel(const float* __restrict__ q,
                                 const unsigned short* __restrict__ kb,
                                 const unsigned short* __restrict__ vt_,
                                 float* __restrict__ out) {
    // P round-trip buffer, WAVE-PRIVATE ([w] major) -> no block barrier needed,
    // only in-wave lgkmcnt ordering (DS ops are in-order per wave).
    __shared__ __align__(16) unsigned short p_lds[4][16][72];

    // bh->XCD-pinned remap: all 32 itile-blocks of a bh land on ONE XCD
    // (xcd = bid%8 empirically). 4 bh per XCD -> 4MB K+V working set ~= L2.
    // Reflected itile per hi pairs light+heavy blocks on each CU (sum = const).
    int bid = blockIdx.x;
    int x    = bid & 7;          // XCD id
    int t_   = bid >> 3;
    int slot = t_ & 31;
    int hi   = t_ >> 5;          // 0..3
    int itile = (hi & 1) ? (31 - slot) : slot;
    int bh = hi * 8 + x;
    int b = bh >> 4, h = bh & 15;

    int lane = threadIdx.x & 63;
    int w = threadIdx.x >> 6;
    int g = lane >> 4;                  // 0..3
    int c = lane & 15;                  // 0..15

    int i_wave = itile * QBLK + w * 16;

    float ex = exp2f((float)(-5 - h));
    float gamma = 1.0f - ex;
    float log2g = log1pf(-ex) * 1.44269504088896f;   // accurate near gamma~1

    // column decay factors: gamma^-(16*nt + c)   (max gamma^-63 ~ 7.4, safe)
    float bcol[4];
    bcol[0] = exp2f(log2g * (float)(-c));
    float g16i = exp2f(log2g * (-16.0f));
    bcol[1] = bcol[0] * g16i; bcol[2] = bcol[1] * g16i; bcol[3] = bcol[2] * g16i;

    // row decay base for jt=0: gamma^(i_wave + g*4); updated *= gamma^-64 per jt
    float arow0 = exp2f(log2g * (float)(i_wave + g * 4));
    float gm64i = exp2f(log2g * (-64.0f));

    // hoist Q fragments (A operand: m = lane&15, k contiguous per 16-lane grp)
    bf16x8 qf[4];
    {
        const float* qp = q + ((size_t)bh * L_ + (i_wave + c)) * DK_ + g * 8;
        #pragma unroll
        for (int ks = 0; ks < 4; ++ks) {
            float4 f0 = *(const float4*)(qp + ks * 32);
            float4 f1 = *(const float4*)(qp + ks * 32 + 4);
            union { bf16x8 v; unsigned short u[8]; } A;
            A.u[0]=f2bf(f0.x); A.u[1]=f2bf(f0.y); A.u[2]=f2bf(f0.z); A.u[3]=f2bf(f0.w);
            A.u[4]=f2bf(f1.x); A.u[5]=f2bf(f1.y); A.u[6]=f2bf(f1.z); A.u[7]=f2bf(f1.w);
            qf[ks] = A.v;
        }
    }

    const unsigned short* kbp = kb  + (size_t)bh * L_ * DK_;
    const unsigned short* vtp = vt_ + (size_t)bh * DV_ * L_;

    f32x4 o[8];
    f32x4 zero = {0.f, 0.f, 0.f, 0.f};
    #pragma unroll
    for (int nt = 0; nt < 8; ++nt) o[nt] = zero;
    float rowsum[4] = {0.f, 0.f, 0.f, 0.f};

    for (int jt = 0; jt <= itile; ++jt) {
        int j_base = jt * KVBLK;

        // ---- S = Q K^T (16x64), B-frags straight from bf16 K (gemm_bt style)
        f32x4 s[4];
        #pragma unroll
        for (int nt = 0; nt < 4; ++nt) s[nt] = zero;
        #pragma unroll
        for (int ks = 0; ks < 4; ++ks) {
            #pragma unroll
            for (int nt = 0; nt < 4; ++nt) {
                const unsigned short* kp =
                    kbp + (size_t)(j_base + nt * 16 + c) * DK_ + ks * 32 + g * 8;
                bf16x8 bfrag = *(const bf16x8*)kp;
                s[nt] = __builtin_amdgcn_mfma_f32_16x16x32_bf16(qf[ks], bfrag, s[nt], 0, 0, 0);
            }
        }

        // ---- decay: w(i,j) = gamma^(i - j_base) * gamma^-(j - j_base)
        float arow[4];
        arow[0] = arow0;
        arow[1] = arow[0] * gamma; arow[2] = arow[1] * gamma; arow[3] = arow[2] * gamma;
        arow0 *= gm64i;   // advance to next jt

        if (jt == itile) {   // diagonal tile: per-element causal mask
            #pragma unroll
            for (int nt = 0; nt < 4; ++nt) {
                int j = j_base + nt * 16 + c;
                #pragma unroll
                for (int r = 0; r < 4; ++r) {
                    int i = i_wave + g * 4 + r;
                    float wgt = (j <= i) ? arow[r] * bcol[nt] : 0.0f;
                    float val = s[nt][r] * wgt;
                    rowsum[r] += val;
                    p_lds[w][g * 4 + r][nt * 16 + c] = f2bf(val);
                }
            }
        } else {             // strictly-lower tile: no mask needed
            #pragma unroll
            for (int nt = 0; nt < 4; ++nt) {
                #pragma unroll
                for (int r = 0; r < 4; ++r) {
                    float val = s[nt][r] * (arow[r] * bcol[nt]);
                    rowsum[r] += val;
                    p_lds[w][g * 4 + r][nt * 16 + c] = f2bf(val);
                }
            }
        }
        // in-wave ordering only: drain DS writes before cross-lane DS reads
        asm volatile("s_waitcnt lgkmcnt(0)" ::: "memory");
        __builtin_amdgcn_sched_barrier(0);

        // ---- O += P V ; B-frags straight from bf16 V^T
        #pragma unroll
        for (int ks = 0; ks < 2; ++ks) {
            bf16x8 pa = *(const bf16x8*)&p_lds[w][c][ks * 32 + g * 8];
            #pragma unroll
            for (int nt = 0; nt < 8; ++nt) {
                const unsigned short* vp =
                    vtp + (size_t)(nt * 16 + c) * L_ + j_base + ks * 32 + g * 8;
                bf16x8 vb = *(const bf16x8*)vp;
                o[nt] = __builtin_amdgcn_mfma_f32_16x16x32_bf16(pa, vb, o[nt], 0, 0, 0);
            }
        }
        // no barrier: DS in-order per wave + compiler aliasing keeps next-tile
        // p_lds writes behind these reads
    }

    // ---- epilogue: denom + RMSNorm (reductions within 16-lane groups) ----
    #pragma unroll
    for (int r = 0; r < 4; ++r) {
        float vsum = rowsum[r];
        vsum += __shfl_xor(vsum, 1);
        vsum += __shfl_xor(vsum, 2);
        vsum += __shfl_xor(vsum, 4);
        vsum += __shfl_xor(vsum, 8);
        rowsum[r] = 1.0f / fmaxf(1.0f, fabsf(vsum));
    }
    #pragma unroll
    for (int nt = 0; nt < 8; ++nt) {
        #pragma unroll
        for (int r = 0; r < 4; ++r) o[nt][r] *= rowsum[r];
    }
    float scale[4];
    #pragma unroll
    for (int r = 0; r < 4; ++r) {
        float ss = 0.f;
        #pragma unroll
        for (int nt = 0; nt < 8; ++nt) ss += o[nt][r] * o[nt][r];
        ss += __shfl_xor(ss, 1);
        ss += __shfl_xor(ss, 2);
        ss += __shfl_xor(ss, 4);
        ss += __shfl_xor(ss, 8);
        scale[r] = rsqrtf(ss * (1.0f / 128.0f) + 1e-6f);
    }
    #pragma unroll
    for (int r = 0; r < 4; ++r) {
        int i = i_wave + g * 4 + r;
        float* op = out + (((size_t)b * L_ + i) * H_ + h) * DV_ + c;
        #pragma unroll
        for (int nt = 0; nt < 8; ++nt) op[nt * 16] = o[nt][r] * scale[r];
    }
}

// ---- fp32 fixup for row i=0 (single-term row: eps-magnified bf16 error) ----
__global__ void fix_row0_kernel(const float* __restrict__ q,
                                const float* __restrict__ k,
                                const float* __restrict__ v,
                                float* __restrict__ out) {
    int bh = blockIdx.x;            // 0..31
    int lane = threadIdx.x;         // 0..63
    const float* qp = q + (size_t)bh * L_ * DK_;
    const float* kp = k + (size_t)bh * L_ * DK_;
    const float* vp = v + (size_t)bh * L_ * DV_;
    float part = qp[lane] * kp[lane] + qp[lane + 64] * kp[lane + 64];
    #pragma unroll
    for (int mm = 1; mm < 64; mm <<= 1) part += __shfl_xor(part, mm);
    float r00 = part;
    float cf = r00 / fmaxf(1.0f, fabsf(r00));
    float o0 = cf * vp[lane], o1 = cf * vp[lane + 64];
    float ss = o0 * o0 + o1 * o1;
    #pragma unroll
    for (int mm = 1; mm < 64; mm <<= 1) ss += __shfl_xor(ss, mm);
    float sc = rsqrtf(ss * (1.0f / 128.0f) + 1e-6f);
    int b = bh >> 4, h = bh & 15;
    float* op = out + ((size_t)b * L_ * H_ + h) * DV_;   // i = 0
    op[lane] = o0 * sc;
    op[lane + 64] = o1 * sc;
}

extern "C" void kernel_launch(void* const* d_in, const int* in_sizes, int n_in,
                              void* d_out, int out_size, void* d_ws, size_t ws_size,
                              hipStream_t stream) {
    const float* q = (const float*)d_in[0];
    const float* k = (const float*)d_in[1];
    const float* v = (const float*)d_in[2];
    // d_in[3] decay_mask (256MB) and d_in[4] intra_decay are recomputed on the fly
    float* out = (float*)d_out;

    unsigned short* kb = (unsigned short*)d_ws;                 // 16 MB
    unsigned short* vt = kb + (size_t)B_ * H_ * L_ * DK_;       // 16 MB

    int n4 = B_ * H_ * L_ * DK_ / 4;
    cvt_bf16_kernel<<<2048, 256, 0, stream>>>(k, kb, n4);
    transpose_v_kernel<<<B_ * H_ * (L_ / 64), 256, 0, stream>>>(v, vt);
    retention_kernel<<<B_ * H_ * NIT, 256, 0, stream>>>(q, kb, vt, out);
    fix_row0_kernel<<<B_ * H_, 64, 0, stream>>>(q, k, v, out);
}

// Round 3
// 105.305 us; speedup vs baseline: 2.8888x; 2.7610x over previous
//
#include <hip/hip_runtime.h>
#include <hip/hip_bf16.h>
#include <math.h>

// SelfRetentionV1: B=2,H=16,L=2048,DK=128,DV=128
// out[b,l,h,d] = RMSNorm_d( (QK^T * gamma^(i-j) / max(1,|rowsum|)) @ V )
#define B_ 2
#define H_ 16
#define L_ 2048
#define DK_ 128
#define DV_ 128
#define QBLK 64
#define KVBLK 64
#define NIT (L_/QBLK)   // 32

typedef __bf16 bf16x8 __attribute__((ext_vector_type(8)));
typedef float  f32x4  __attribute__((ext_vector_type(4)));

static __device__ __forceinline__ unsigned short f2bf(float f) {
    union { float f; unsigned int u; } x; x.f = f;
    unsigned int r = x.u + 0x7fffu + ((x.u >> 16) & 1u);  // RNE
    return (unsigned short)(r >> 16);
}

// async global->LDS, 16B per lane; LDS dest = wave-uniform base + lane*16
static __device__ __forceinline__ void gload_lds16(const void* g, void* l) {
    __builtin_amdgcn_global_load_lds(
        (const __attribute__((address_space(1))) unsigned int*)g,
        (__attribute__((address_space(3))) unsigned int*)l,
        16, 0, 0);
}

// K tile rows are 256B: swizzle bits 4-6 by row&7 (involution, row bits >=8)
#define KSWZ(d) ((d) ^ ((((d) >> 8) & 7) << 4))
// V tile rows are 128B: row bits >=7
#define VSWZ(d) ((d) ^ ((((d) >> 7) & 7) << 4))

// ---- pre-kernel 1: fp32 -> bf16 flat convert (K) ----
__global__ void cvt_bf16_kernel(const float* __restrict__ in,
                                unsigned short* __restrict__ out, int n4) {
    int i = blockIdx.x * blockDim.x + threadIdx.x;
    int stride = gridDim.x * blockDim.x;
    for (; i < n4; i += stride) {
        float4 f = ((const float4*)in)[i];
        uint2 o;
        o.x = (unsigned)f2bf(f.x) | ((unsigned)f2bf(f.y) << 16);
        o.y = (unsigned)f2bf(f.z) | ((unsigned)f2bf(f.w) << 16);
        ((uint2*)out)[i] = o;
    }
}

// ---- pre-kernel 2: V[bh][l][dv] -> VT[bh][dv][l], bf16 ----
__global__ void transpose_v_kernel(const float* __restrict__ v,
                                   unsigned short* __restrict__ vt) {
    __shared__ unsigned short lds[64][130];   // +2 pad: col reads conflict-free
    int blk = blockIdx.x;
    int ltile = blk & (L_/64 - 1);
    int bh = blk / (L_/64);
    const float* vp = v + ((size_t)bh * L_ + (size_t)ltile * 64) * DV_;
    unsigned short* vo = vt + (size_t)bh * DV_ * L_ + ltile * 64;
    int t = threadIdx.x;
    int r0 = t >> 5, c0 = (t & 31) * 4;
    #pragma unroll
    for (int it = 0; it < 8; ++it) {
        int row = r0 + 8 * it;
        float4 f = *(const float4*)(vp + row * DV_ + c0);
        lds[row][c0 + 0] = f2bf(f.x);
        lds[row][c0 + 1] = f2bf(f.y);
        lds[row][c0 + 2] = f2bf(f.z);
        lds[row][c0 + 3] = f2bf(f.w);
    }
    __syncthreads();
    int dvb = t >> 3, seg = t & 7;
    #pragma unroll
    for (int ot = 0; ot < 4; ++ot) {
        int dv = dvb + 32 * ot;
        unsigned short a0 = lds[seg*8+0][dv], a1 = lds[seg*8+1][dv];
        unsigned short a2 = lds[seg*8+2][dv], a3 = lds[seg*8+3][dv];
        unsigned short a4 = lds[seg*8+4][dv], a5 = lds[seg*8+5][dv];
        unsigned short a6 = lds[seg*8+6][dv], a7 = lds[seg*8+7][dv];
        uint4 st;
        st.x = (unsigned)a0 | ((unsigned)a1 << 16);
        st.y = (unsigned)a2 | ((unsigned)a3 << 16);
        st.z = (unsigned)a4 | ((unsigned)a5 << 16);
        st.w = (unsigned)a6 | ((unsigned)a7 << 16);
        *(uint4*)(vo + (size_t)dv * L_ + seg * 8) = st;
    }
}

// ---- main kernel: 4 waves x 16 Q-rows; K/V LDS-staged, double-buffered ----
__launch_bounds__(256, 2)
__global__ void retention_kernel(const float* __restrict__ q,
                                 const unsigned short* __restrict__ kb,
                                 const unsigned short* __restrict__ vt_,
                                 float* __restrict__ out) {
    // K tile [64][128] bf16 (16KB), V^T tile [128][64] bf16 (16KB), x2 dbuf
    __shared__ __align__(16) unsigned short kbuf[2][64 * 128];
    __shared__ __align__(16) unsigned short vbuf[2][128 * 64];
    __shared__ __align__(16) unsigned short p_lds[4][16][72];  // wave-private

    // bh->XCD-pinned remap (xcd = bid%8): 4 bh per XCD -> ~4MB K+V ~= L2
    int bid = blockIdx.x;
    int x    = bid & 7;          // XCD id
    int t_   = bid >> 3;
    int slot = t_ & 31;
    int hi   = t_ >> 5;          // 0..3
    int itile = (hi & 1) ? (31 - slot) : slot;
    int bh = hi * 8 + x;
    int b = bh >> 4, h = bh & 15;

    int tid = threadIdx.x;
    int lane = tid & 63;
    int w = tid >> 6;
    int g = lane >> 4;                  // 0..3
    int c = lane & 15;                  // 0..15

    int i_wave = itile * QBLK + w * 16;

    const unsigned short* kbp = kb  + (size_t)bh * L_ * DK_;
    const unsigned short* vtp = vt_ + (size_t)bh * DV_ * L_;

    // ---- stage tile 0 first (DMA runs under the setup below) ----
    {
        const char* ksrc = (const char*)kbp;          // rows 0..63
        const char* vsrc = (const char*)vtp;          // j offset 0
        char* kdst = (char*)&kbuf[0][0];
        char* vdst = (char*)&vbuf[0][0];
        #pragma unroll
        for (int is = 0; is < 4; ++is) {
            int dw = is * 4096 + w * 1024;            // wave-uniform dest
            int d  = dw + lane * 16;
            gload_lds16(ksrc + KSWZ(d), kdst + dw);
            int sv = VSWZ(d);
            gload_lds16(vsrc + (size_t)(sv >> 7) * (L_ * 2) + (sv & 127), vdst + dw);
        }
    }

    float ex = exp2f((float)(-5 - h));
    float gamma = 1.0f - ex;
    float log2g = log1pf(-ex) * 1.44269504088896f;   // accurate near gamma~1

    // column decay factors: gamma^-(16*nt + c)   (max gamma^-63 ~ 7.4, safe)
    float bcol[4];
    bcol[0] = exp2f(log2g * (float)(-c));
    float g16i = exp2f(log2g * (-16.0f));
    bcol[1] = bcol[0] * g16i; bcol[2] = bcol[1] * g16i; bcol[3] = bcol[2] * g16i;

    // row decay base for jt=0: gamma^(i_wave + g*4); *= gamma^-64 per jt
    float arow0 = exp2f(log2g * (float)(i_wave + g * 4));
    float gm64i = exp2f(log2g * (-64.0f));

    // hoist Q fragments (A operand: m = lane&15, k contiguous per 16-lane grp)
    bf16x8 qf[4];
    {
        const float* qp = q + ((size_t)bh * L_ + (i_wave + c)) * DK_ + g * 8;
        #pragma unroll
        for (int ks = 0; ks < 4; ++ks) {
            float4 f0 = *(const float4*)(qp + ks * 32);
            float4 f1 = *(const float4*)(qp + ks * 32 + 4);
            union { bf16x8 v; unsigned short u[8]; } A;
            A.u[0]=f2bf(f0.x); A.u[1]=f2bf(f0.y); A.u[2]=f2bf(f0.z); A.u[3]=f2bf(f0.w);
            A.u[4]=f2bf(f1.x); A.u[5]=f2bf(f1.y); A.u[6]=f2bf(f1.z); A.u[7]=f2bf(f1.w);
            qf[ks] = A.v;
        }
    }

    f32x4 o[8];
    f32x4 zero = {0.f, 0.f, 0.f, 0.f};
    #pragma unroll
    for (int nt = 0; nt < 8; ++nt) o[nt] = zero;
    float rowsum[4] = {0.f, 0.f, 0.f, 0.f};

    int swz = (c & 7) << 4;   // read-side XOR (row&7 == c&7 for rows nt*16+c)

    __syncthreads();          // implicit vmcnt(0) drain: buf0 resident
    int cur = 0;

    for (int jt = 0; jt <= itile; ++jt) {
        // ---- issue next tile's stage (lands during compute below) ----
        if (jt < itile) {
            int jb = (jt + 1) * KVBLK;
            const char* ksrc = (const char*)(kbp + (size_t)jb * DK_);
            const char* vsrc = (const char*)(vtp + jb);
            char* kdst = (char*)&kbuf[cur ^ 1][0];
            char* vdst = (char*)&vbuf[cur ^ 1][0];
            #pragma unroll
            for (int is = 0; is < 4; ++is) {
                int dw = is * 4096 + w * 1024;
                int d  = dw + lane * 16;
                gload_lds16(ksrc + KSWZ(d), kdst + dw);
                int sv = VSWZ(d);
                gload_lds16(vsrc + (size_t)(sv >> 7) * (L_ * 2) + (sv & 127), vdst + dw);
            }
        }

        const char* kb_c = (const char*)&kbuf[cur][0];
        const char* vb_c = (const char*)&vbuf[cur][0];

        // ---- S = Q K^T (16x64) from swizzled LDS ----
        f32x4 s[4];
        #pragma unroll
        for (int nt = 0; nt < 4; ++nt) s[nt] = zero;
        #pragma unroll
        for (int ks = 0; ks < 4; ++ks) {
            #pragma unroll
            for (int nt = 0; nt < 4; ++nt) {
                int krow = nt * 16 + c;
                bf16x8 bfrag = *(const bf16x8*)(kb_c + krow * 256 + ((ks * 64 + g * 16) ^ swz));
                s[nt] = __builtin_amdgcn_mfma_f32_16x16x32_bf16(qf[ks], bfrag, s[nt], 0, 0, 0);
            }
        }

        // ---- decay: w(i,j) = gamma^(i - j_base) * gamma^-(j - j_base)
        float arow[4];
        arow[0] = arow0;
        arow[1] = arow[0] * gamma; arow[2] = arow[1] * gamma; arow[3] = arow[2] * gamma;
        arow0 *= gm64i;   // advance to next jt

        if (jt == itile) {   // diagonal tile: per-element causal mask
            #pragma unroll
            for (int nt = 0; nt < 4; ++nt) {
                int j = jt * KVBLK + nt * 16 + c;
                #pragma unroll
                for (int r = 0; r < 4; ++r) {
                    int i = i_wave + g * 4 + r;
                    float wgt = (j <= i) ? arow[r] * bcol[nt] : 0.0f;
                    float val = s[nt][r] * wgt;
                    rowsum[r] += val;
                    p_lds[w][g * 4 + r][nt * 16 + c] = f2bf(val);
                }
            }
        } else {             // strictly-lower tile: no mask needed
            #pragma unroll
            for (int nt = 0; nt < 4; ++nt) {
                #pragma unroll
                for (int r = 0; r < 4; ++r) {
                    float val = s[nt][r] * (arow[r] * bcol[nt]);
                    rowsum[r] += val;
                    p_lds[w][g * 4 + r][nt * 16 + c] = f2bf(val);
                }
            }
        }
        // wave-private p_lds: per-wave in-order DS + compiler may-alias ordering
        // give write->read correctness without any block barrier here.

        // ---- O += P V from swizzled LDS V^T ----
        #pragma unroll
        for (int ks = 0; ks < 2; ++ks) {
            bf16x8 pa = *(const bf16x8*)&p_lds[w][c][ks * 32 + g * 8];
            #pragma unroll
            for (int nt = 0; nt < 8; ++nt) {
                int vrow = nt * 16 + c;
                bf16x8 vb = *(const bf16x8*)(vb_c + vrow * 128 + ((ks * 64 + g * 16) ^ swz));
                o[nt] = __builtin_amdgcn_mfma_f32_16x16x32_bf16(pa, vb, o[nt], 0, 0, 0);
            }
        }

        // one barrier per tile: drains the stage issued above (had full compute
        // to land) and protects buf[cur^1] reads before next iter's overwrite
        __syncthreads();
        cur ^= 1;
    }

    // ---- epilogue: denom + RMSNorm (reductions within 16-lane groups) ----
    #pragma unroll
    for (int r = 0; r < 4; ++r) {
        float vsum = rowsum[r];
        vsum += __shfl_xor(vsum, 1);
        vsum += __shfl_xor(vsum, 2);
        vsum += __shfl_xor(vsum, 4);
        vsum += __shfl_xor(vsum, 8);
        rowsum[r] = 1.0f / fmaxf(1.0f, fabsf(vsum));
    }
    #pragma unroll
    for (int nt = 0; nt < 8; ++nt) {
        #pragma unroll
        for (int r = 0; r < 4; ++r) o[nt][r] *= rowsum[r];
    }
    float scale[4];
    #pragma unroll
    for (int r = 0; r < 4; ++r) {
        float ss = 0.f;
        #pragma unroll
        for (int nt = 0; nt < 8; ++nt) ss += o[nt][r] * o[nt][r];
        ss += __shfl_xor(ss, 1);
        ss += __shfl_xor(ss, 2);
        ss += __shfl_xor(ss, 4);
        ss += __shfl_xor(ss, 8);
        scale[r] = rsqrtf(ss * (1.0f / 128.0f) + 1e-6f);
    }
    #pragma unroll
    for (int r = 0; r < 4; ++r) {
        int i = i_wave + g * 4 + r;
        float* op = out + (((size_t)b * L_ + i) * H_ + h) * DV_ + c;
        #pragma unroll
        for (int nt = 0; nt < 8; ++nt) op[nt * 16] = o[nt][r] * scale[r];
    }
}

// ---- fp32 fixup for row i=0 (single-term row: eps-magnified bf16 error) ----
__global__ void fix_row0_kernel(const float* __restrict__ q,
                                const float* __restrict__ k,
                                const float* __restrict__ v,
                                float* __restrict__ out) {
    int bh = blockIdx.x;            // 0..31
    int lane = threadIdx.x;         // 0..63
    const float* qp = q + (size_t)bh * L_ * DK_;
    const float* kp = k + (size_t)bh * L_ * DK_;
    const float* vp = v + (size_t)bh * L_ * DV_;
    float part = qp[lane] * kp[lane] + qp[lane + 64] * kp[lane + 64];
    #pragma unroll
    for (int mm = 1; mm < 64; mm <<= 1) part += __shfl_xor(part, mm);
    float r00 = part;
    float cf = r00 / fmaxf(1.0f, fabsf(r00));
    float o0 = cf * vp[lane], o1 = cf * vp[lane + 64];
    float ss = o0 * o0 + o1 * o1;
    #pragma unroll
    for (int mm = 1; mm < 64; mm <<= 1) ss += __shfl_xor(ss, mm);
    float sc = rsqrtf(ss * (1.0f / 128.0f) + 1e-6f);
    int b = bh >> 4, h = bh & 15;
    float* op = out + ((size_t)b * L_ * H_ + h) * DV_;   // i = 0
    op[lane] = o0 * sc;
    op[lane + 64] = o1 * sc;
}

extern "C" void kernel_launch(void* const* d_in, const int* in_sizes, int n_in,
                              void* d_out, int out_size, void* d_ws, size_t ws_size,
                              hipStream_t stream) {
    const float* q = (const float*)d_in[0];
    const float* k = (const float*)d_in[1];
    const float* v = (const float*)d_in[2];
    // d_in[3] decay_mask (256MB) and d_in[4] intra_decay are recomputed on the fly
    float* out = (float*)d_out;

    unsigned short* kb = (unsigned short*)d_ws;                 // 16 MB
    unsigned short* vt = kb + (size_t)B_ * H_ * L_ * DK_;       // 16 MB

    int n4 = B_ * H_ * L_ * DK_ / 4;
    cvt_bf16_kernel<<<2048, 256, 0, stream>>>(k, kb, n4);
    transpose_v_kernel<<<B_ * H_ * (L_ / 64), 256, 0, stream>>>(v, vt);
    retention_kernel<<<B_ * H_ * NIT, 256, 0, stream>>>(q, kb, vt, out);
    fix_row0_kernel<<<B_ * H_, 64, 0, stream>>>(q, k, v, out);
}